// Round 16
// baseline (187.445 us; speedup 1.0000x reference)
//
#include <hip/hip_runtime.h>

typedef unsigned short u16;
typedef unsigned char u8;
typedef float f32x4 __attribute__((ext_vector_type(4)));
typedef int i32x8 __attribute__((ext_vector_type(8)));

#define CH 512
#define HW 4096
#define TOKENS 16384
#define NGRP 32

__device__ __forceinline__ u8 f2fp8(float f) {   // OCP e4m3fn, RNE+sat
  return (u8)(__builtin_amdgcn_cvt_pk_fp8_f32(f, f, 0, false) & 0xff);
}
__device__ __forceinline__ unsigned f2fp8x4(float a, float b, float c, float d) {
  int lo = __builtin_amdgcn_cvt_pk_fp8_f32(a, b, 0, false);
  return (unsigned)__builtin_amdgcn_cvt_pk_fp8_f32(c, d, lo, true);
}
// fp4 e2m1 encode of 4*x (pre-scale x4; MFMA dequants with E8M0 scale 125 = 2^-2).
__device__ __forceinline__ unsigned nib4(float x) {
  float a = fabsf(x) * 4.0f;
  unsigned c = (unsigned)(a >= 0.25f) + (a >= 0.75f) + (a >= 1.25f) + (a >= 1.75f) +
               (a >= 2.5f) + (a >= 3.5f) + (a >= 5.0f);
  return c | ((__float_as_uint(x) >> 28) & 8u);
}
__device__ __forceinline__ u16 pk4(float a, float b, float c, float d) {
  return (u16)(nib4(a) | (nib4(b) << 4) | (nib4(c) << 8) | (nib4(d) << 12));
}

// async global->LDS, 16B per lane
#define GLOAD16(gp, lp)                                                        \
  __builtin_amdgcn_global_load_lds(                                            \
      (const __attribute__((address_space(1))) unsigned int*)(const void*)(gp),\
      (__attribute__((address_space(3))) unsigned int*)(void*)(lp), 16, 0, 0)

// fp8 frag read: 32B at swizzled offset (rows 128B, granule ^= row&7)
#define RD8(dst, buf, row) do {                                                \
    int base_ = (row) * 128, sw_ = ((row) & 7) << 4;                           \
    uint4 lo_ = *(const uint4*)(&buf[base_ + ((h * 32) ^ sw_)]);               \
    uint4 hi_ = *(const uint4*)(&buf[base_ + ((h * 32 + 16) ^ sw_)]);          \
    dst[0] = (int)lo_.x; dst[1] = (int)lo_.y; dst[2] = (int)lo_.z;             \
    dst[3] = (int)lo_.w; dst[4] = (int)hi_.x; dst[5] = (int)hi_.y;             \
    dst[6] = (int)hi_.z; dst[7] = (int)hi_.w;                                  \
  } while (0)

// ---------------- GroupNorm stats: one block per (b,g) ----------------
__global__ void gn_stats(const float* __restrict__ x, float2* __restrict__ stats) {
  int bg = blockIdx.x;              // 0..127
  int b = bg >> 5, g = bg & 31;
  const float* base = x + (size_t)b * HW * CH + g * 16;
  float s = 0.f, s2 = 0.f;
  for (int p = threadIdx.x; p < HW; p += 256) {
    const float4* row = (const float4*)(base + (size_t)p * CH);
#pragma unroll
    for (int q = 0; q < 4; ++q) {
      float4 v = row[q];
      s += v.x + v.y + v.z + v.w;
      s2 += v.x * v.x + v.y * v.y + v.z * v.z + v.w * v.w;
    }
  }
#pragma unroll
  for (int o = 32; o; o >>= 1) { s += __shfl_down(s, o); s2 += __shfl_down(s2, o); }
  __shared__ float rs[4], rs2[4];
  int wid = threadIdx.x >> 6, lane = threadIdx.x & 63;
  if (lane == 0) { rs[wid] = s; rs2[wid] = s2; }
  __syncthreads();
  if (threadIdx.x == 0) {
    float S = rs[0] + rs[1] + rs[2] + rs[3];
    float S2 = rs2[0] + rs2[1] + rs2[2] + rs2[3];
    float mean = S * (1.f / 65536.f);
    float var = S2 * (1.f / 65536.f) - mean * mean;
    stats[bg] = make_float2(mean, rsqrtf(var + 1e-5f));
  }
}

// ---------------- GroupNorm apply -> xn8 (fp8) ----------------
__global__ void gn_apply8(const float* __restrict__ x, const float* __restrict__ gamma,
                          const float* __restrict__ beta, const float2* __restrict__ stats,
                          u8* __restrict__ xn8) {
  size_t i = (size_t)blockIdx.x * blockDim.x + threadIdx.x;  // chunk of 8 elems
  size_t e0 = i * 8;
  int c = (int)(e0 & (CH - 1));
  size_t t = e0 >> 9;
  int b = (int)(t >> 12);
  float2 st = stats[b * NGRP + (c >> 4)];
  float4 v0 = *(const float4*)(x + t * CH + c);
  float4 v1 = *(const float4*)(x + t * CH + c + 4);
  float4 g0 = *(const float4*)(gamma + c);
  float4 g1 = *(const float4*)(gamma + c + 4);
  float4 b0 = *(const float4*)(beta + c);
  float4 b1 = *(const float4*)(beta + c + 4);
  float o[8];
  o[0] = (v0.x - st.x) * st.y * g0.x + b0.x;
  o[1] = (v0.y - st.x) * st.y * g0.y + b0.y;
  o[2] = (v0.z - st.x) * st.y * g0.z + b0.z;
  o[3] = (v0.w - st.x) * st.y * g0.w + b0.w;
  o[4] = (v1.x - st.x) * st.y * g1.x + b1.x;
  o[5] = (v1.y - st.x) * st.y * g1.y + b1.y;
  o[6] = (v1.z - st.x) * st.y * g1.z + b1.z;
  o[7] = (v1.w - st.x) * st.y * g1.w + b1.w;
  uint2 pk;
  pk.x = f2fp8x4(o[0], o[1], o[2], o[3]);
  pk.y = f2fp8x4(o[4], o[5], o[6], o[7]);
  *(uint2*)(xn8 + e0) = pk;
}

// ---------------- transpose 512x512 weights fp32 -> fp8 (T[d][c] = W[c][d]) ----------------
__global__ void transpose_w8(const float* __restrict__ W0, const float* __restrict__ W1,
                             const float* __restrict__ W2, const float* __restrict__ W3,
                             u8* __restrict__ T0, u8* __restrict__ T1,
                             u8* __restrict__ T2, u8* __restrict__ T3) {
  const float* W; u8* T;
  switch (blockIdx.z) {
    case 0: W = W0; T = T0; break;
    case 1: W = W1; T = T1; break;
    case 2: W = W2; T = T2; break;
    default: W = W3; T = T3; break;
  }
  __shared__ float tile[32][33];
  int tx = threadIdx.x, ty = threadIdx.y;
  int x0 = blockIdx.x * 32, y0 = blockIdx.y * 32;
#pragma unroll
  for (int r = 0; r < 32; r += 8) tile[ty + r][tx] = W[(size_t)(y0 + ty + r) * CH + x0 + tx];
  __syncthreads();
#pragma unroll
  for (int r = 0; r < 32; r += 8) T[(size_t)(x0 + ty + r) * CH + y0 + tx] = f2fp8(tile[tx][ty + r]);
}

// ---- QKV: MX-fp8 GEMM (xn8 x Wqkv8), epilogue -> fp4 Q4,K4 (kappa-c packed) + fp4 V4t ----
__global__ __launch_bounds__(256) void qkvmx(const u8* __restrict__ A,
                                             const u8* __restrict__ Bt,
                                             const float* __restrict__ bq,
                                             const float* __restrict__ bk,
                                             const float* __restrict__ bv,
                                             u8* __restrict__ Q4, u8* __restrict__ K4,
                                             u8* __restrict__ V4) {
  constexpr int BK = 128;
  const int K = CH;
  __shared__ __align__(16) u8 lA[128 * BK];
  __shared__ __align__(16) u8 lB[128 * BK];
  const int bm = blockIdx.y * 128, bn = blockIdx.x * 128;
  const int tid = threadIdx.x, lane = tid & 63, wid = tid >> 6;
  const int wm = (wid >> 1) * 64, wn = (wid & 1) * 64;
  const int r0 = lane & 15, h = lane >> 4;

  const int srow = lane >> 3;
  const int scol = ((lane & 7) * 16) ^ ((srow & 7) << 4);
  size_t aoff[4], boff[4];
#pragma unroll
  for (int s = 0; s < 4; ++s) {
    int row = wid * 32 + s * 8 + srow;
    aoff[s] = (size_t)(bm + row) * K + scol;
    boff[s] = (size_t)(bn + row) * K + scol;
  }

  f32x4 acc[4][4] = {};
  for (int kt = 0; kt < K; kt += BK) {
    __syncthreads();
#pragma unroll
    for (int s = 0; s < 4; ++s) {
      GLOAD16(A + aoff[s] + kt, &lA[(wid * 4 + s) * 1024]);
      GLOAD16(Bt + boff[s] + kt, &lB[(wid * 4 + s) * 1024]);
    }
    __syncthreads();
    i32x8 bf[4];
#pragma unroll
    for (int j = 0; j < 4; ++j) RD8(bf[j], lB, wn + j * 16 + r0);
#pragma unroll
    for (int i = 0; i < 4; ++i) {
      i32x8 af;
      RD8(af, lA, wm + i * 16 + r0);
#pragma unroll
      for (int j = 0; j < 4; ++j)
        acc[i][j] = __builtin_amdgcn_mfma_scale_f32_16x16x128_f8f6f4(
            af, bf[j], acc[i][j], 0, 0, 0, 127, 0, 127);
    }
  }

  // epilogue: D layout col(n)=lane&15, row=(lane>>4)*4+r; chunk uniform per (block, wn)
  const int chn = (bn + wn) >> 9;
  const int nb = (bn + wn) & 511;
  if (chn == 2) {                     // V: fp4, [bb][CH][HW/2], keys 4-consecutive -> u16
#pragma unroll
    for (int j = 0; j < 4; ++j) {
      int nn = nb + j * 16 + r0;
      float bvv = bv[nn];
#pragma unroll
      for (int i = 0; i < 4; ++i) {
        int m0 = bm + wm + i * 16 + h * 4;
        int bb = m0 >> 12, tl = m0 & (HW - 1);
        *(u16*)(V4 + ((size_t)bb * CH + nn) * (HW / 2) + (tl >> 1)) =
            pk4(acc[i][j][0] + bvv, acc[i][j][1] + bvv,
                acc[i][j][2] + bvv, acc[i][j][3] + bvv);
      }
    }
  } else {                            // Q/K: fp4, rows 256B, kappa-c packed u16
    u8* P4 = chn == 0 ? Q4 : K4;
    const float* bb_ = chn == 0 ? bq : bk;
    float bj[4];
#pragma unroll
    for (int j = 0; j < 4; ++j) bj[j] = bb_[nb + j * 16 + r0];
#pragma unroll
    for (int i = 0; i < 4; ++i) {
#pragma unroll
      for (int r = 0; r < 4; ++r) {
        int m0r = bm + wm + i * 16 + h * 4 + r;
        *(u16*)(P4 + (size_t)m0r * 256 + (nb >> 1) + 2 * r0) =
            pk4(acc[i][0][r] + bj[0], acc[i][1][r] + bj[1],
                acc[i][2][r] + bj[2], acc[i][3][r] + bj[3]);
      }
    }
  }
}

// ---- FLASH attention v2: Q-tile 32, grid 512 (2 blocks/CU), swapped QK^T ----
// Block = 32 queries of one batch; 8 waves; loops 32 KV-tiles of 128 keys.
// S-phase (per wave, keys [w*16,w*16+16)): S^T = K·Q^T -> lane holds 4 consecutive
// keys at fixed q -> P packed as ONE ds_write_b32 (2-way bank, free). Swizzles are
// 8-value XORs -> all hot LDS reads ~2-way. K,V fp4 straight from L2 (2MB/batch;
// XCD-chunked mapping pins each batch to 2 XCDs). PV: wave owns channels [w*64,+64).
__global__ __launch_bounds__(512, 2) void flash32(const u8* __restrict__ Q4,
                                                  const u8* __restrict__ K4,
                                                  const u8* __restrict__ V4,
                                                  u8* __restrict__ O8, float scl) {
  __shared__ __align__(16) u8 QL[32 * 256];   // 8KB fp4, granule ^= (row&7)
  __shared__ __align__(16) u8 PL[32 * 128];   // 4KB fp8, granule ^= (q&7)
  __shared__ float RSW[8 * 32];               // per-wave rowsum partials

  const int p = blockIdx.x;                   // 0..511
  const int g = (p & 7) * 64 + (p >> 3);      // XCD x serves g in [x*64, x*64+64)
  const int z = g >> 7, qt = g & 127;         // batch (2 XCDs each), q-tile
  const int bm = qt * 32;
  const u8* Q = Q4 + (size_t)z * HW * 256;
  const u8* K = K4 + (size_t)z * HW * 256;
  const u8* V = V4 + (size_t)z * CH * (HW / 2);
  u8* O = O8 + (size_t)z * HW * CH;

  const int tid = threadIdx.x, lane = tid & 63, w = tid >> 6;
  const int r0 = lane & 15, h = lane >> 4;

  // stage Q once: 32 rows x 256B; thread -> 16B; granule (tid&15) ^ (row&7)
  {
    int row = tid >> 4, c0 = (tid & 15) * 16;
    uint4 a = *(const uint4*)(Q + (size_t)(bm + row) * 256 + c0);
    *(uint4*)&QL[row * 256 + (c0 ^ ((row & 7) << 4))] = a;
  }
  __syncthreads();

  f32x4 oacc[2][4] = {};
  float rsum[2] = {0.f, 0.f};

  for (int it = 0; it < 32; ++it) {
    const int k0 = it * 128;
    // ---- S^T = K·Q^T (fp4 x fp4); wave's 16 keys as M, 32 queries as N ----
    f32x4 sacc[2] = {};
#pragma unroll
    for (int ks = 0; ks < 4; ++ks) {
      i32x8 af;                       // K-frag: row = r0-th key of wave block
      {
        uint4 t = *(const uint4*)(K + (size_t)(k0 + w * 16 + r0) * 256 + ks * 64 + h * 16);
        af[0] = (int)t.x; af[1] = (int)t.y; af[2] = (int)t.z; af[3] = (int)t.w;
        af[4] = 0; af[5] = 0; af[6] = 0; af[7] = 0;
      }
#pragma unroll
      for (int j = 0; j < 2; ++j) {   // Q-frag: row = q = j*16 + r0
        uint4 t = *(const uint4*)&QL[(j * 16 + r0) * 256 +
                                     ((ks * 64 + h * 16) ^ ((r0 & 7) << 4))];
        i32x8 bf;
        bf[0] = (int)t.x; bf[1] = (int)t.y; bf[2] = (int)t.z; bf[3] = (int)t.w;
        bf[4] = 0; bf[5] = 0; bf[6] = 0; bf[7] = 0;
        sacc[j] = __builtin_amdgcn_mfma_scale_f32_16x16x128_f8f6f4(
            af, bf, sacc[j], 4, 4, 0, 125, 0, 125);
      }
    }
    // ---- P: lane holds keys {w*16+h*4+r} at q = j*16+r0 -> one u32 per j ----
    __syncthreads();                  // prev iter's PL reads complete
#pragma unroll
    for (int j = 0; j < 2; ++j) {
      float e0 = __expf(sacc[j][0] * scl);
      float e1 = __expf(sacc[j][1] * scl);
      float e2 = __expf(sacc[j][2] * scl);
      float e3 = __expf(sacc[j][3] * scl);
      rsum[j] += e0 + e1 + e2 + e3;
      unsigned pw = (unsigned)f2fp8(e0) | ((unsigned)f2fp8(e1) << 8) |
                    ((unsigned)f2fp8(e2) << 16) | ((unsigned)f2fp8(e3) << 24);
      *(unsigned*)&PL[(j * 16 + r0) * 128 + (((w * 16) ^ ((r0 & 7) << 4)) + h * 4)] = pw;
    }
    __syncthreads();
    // ---- O += P·V^T (fp8 x fp4); wave's 64 channels ----
#pragma unroll
    for (int i = 0; i < 2; ++i) {
      int q = i * 16 + r0;
      int sw = (r0 & 7) << 4;
      uint4 lo = *(const uint4*)&PL[q * 128 + ((h * 32) ^ sw)];
      uint4 hi = *(const uint4*)&PL[q * 128 + ((h * 32 + 16) ^ sw)];
      i32x8 af;
      af[0] = (int)lo.x; af[1] = (int)lo.y; af[2] = (int)lo.z; af[3] = (int)lo.w;
      af[4] = (int)hi.x; af[5] = (int)hi.y; af[6] = (int)hi.z; af[7] = (int)hi.w;
#pragma unroll
      for (int j = 0; j < 4; ++j) {
        uint4 t = *(const uint4*)(V + (size_t)(w * 64 + j * 16 + r0) * (HW / 2) +
                                  it * 64 + h * 16);
        i32x8 bf;
        bf[0] = (int)t.x; bf[1] = (int)t.y; bf[2] = (int)t.z; bf[3] = (int)t.w;
        bf[4] = 0; bf[5] = 0; bf[6] = 0; bf[7] = 0;
        oacc[i][j] = __builtin_amdgcn_mfma_scale_f32_16x16x128_f8f6f4(
            af, bf, oacc[i][j], 0, 4, 0, 127, 0, 125);
      }
    }
  }

  // ---- rowsum: reduce over h-lanes (keys), then across 8 waves; normalize in LDS ----
#pragma unroll
  for (int j = 0; j < 2; ++j) {
    float v = rsum[j];
    v += __shfl_xor(v, 16);
    v += __shfl_xor(v, 32);
    if (h == 0) RSW[w * 32 + j * 16 + r0] = v;
  }
  __syncthreads();
  if (tid < 32) {
    float tot = 0.f;
#pragma unroll
    for (int ww = 0; ww < 8; ++ww) tot += RSW[ww * 32 + tid];
    RSW[tid] = 1.0f / tot;
  }
  __syncthreads();

  // ---- O = fp8(oacc * inv) ----
#pragma unroll
  for (int i = 0; i < 2; ++i)
#pragma unroll
    for (int r = 0; r < 4; ++r) {
      int q = i * 16 + h * 4 + r;
      float inv = RSW[q];
      u8* dst = O + (size_t)(bm + q) * CH + w * 64;
#pragma unroll
      for (int j = 0; j < 4; ++j)
        dst[j * 16 + r0] = f2fp8(oacc[i][j][r] * inv);
    }
}

// ---- proj: MX-fp8 GEMM (O8 x Wp8), f32 out + bias + residual ----
__global__ __launch_bounds__(256) void projmx(const u8* __restrict__ A,
                                              const u8* __restrict__ Bt,
                                              const float* __restrict__ bias,
                                              const float* __restrict__ residual,
                                              float* __restrict__ Cout) {
  constexpr int BK = 128;
  const int K = CH, N = CH;
  __shared__ __align__(16) u8 lA[128 * BK];
  __shared__ __align__(16) u8 lB[128 * BK];
  const int bm = blockIdx.y * 128, bn = blockIdx.x * 128;
  const int tid = threadIdx.x, lane = tid & 63, wid = tid >> 6;
  const int wm = (wid >> 1) * 64, wn = (wid & 1) * 64;
  const int r0 = lane & 15, h = lane >> 4;

  const int srow = lane >> 3;
  const int scol = ((lane & 7) * 16) ^ ((srow & 7) << 4);
  size_t aoff[4], boff[4];
#pragma unroll
  for (int s = 0; s < 4; ++s) {
    int row = wid * 32 + s * 8 + srow;
    aoff[s] = (size_t)(bm + row) * K + scol;
    boff[s] = (size_t)(bn + row) * K + scol;
  }

  f32x4 acc[4][4] = {};
  for (int kt = 0; kt < K; kt += BK) {
    __syncthreads();
#pragma unroll
    for (int s = 0; s < 4; ++s) {
      GLOAD16(A + aoff[s] + kt, &lA[(wid * 4 + s) * 1024]);
      GLOAD16(Bt + boff[s] + kt, &lB[(wid * 4 + s) * 1024]);
    }
    __syncthreads();
    i32x8 bf[4];
#pragma unroll
    for (int j = 0; j < 4; ++j) RD8(bf[j], lB, wn + j * 16 + r0);
#pragma unroll
    for (int i = 0; i < 4; ++i) {
      i32x8 af;
      RD8(af, lA, wm + i * 16 + r0);
#pragma unroll
      for (int j = 0; j < 4; ++j)
        acc[i][j] = __builtin_amdgcn_mfma_scale_f32_16x16x128_f8f6f4(
            af, bf[j], acc[i][j], 0, 0, 0, 127, 0, 127);
    }
  }

#pragma unroll
  for (int j = 0; j < 4; ++j) {
    int n = bn + wn + j * 16 + r0;
    float bvv = bias[n];
#pragma unroll
    for (int i = 0; i < 4; ++i) {
      int m0 = bm + wm + i * 16 + h * 4;
#pragma unroll
      for (int r = 0; r < 4; ++r) {
        size_t idx = (size_t)(m0 + r) * N + n;
        Cout[idx] = acc[i][j][r] + bvv + residual[idx];
      }
    }
  }
}

extern "C" void kernel_launch(void* const* d_in, const int* in_sizes, int n_in,
                              void* d_out, int out_size, void* d_ws, size_t ws_size,
                              hipStream_t stream) {
  (void)in_sizes; (void)n_in; (void)out_size; (void)ws_size;
  const float* x     = (const float*)d_in[0];
  const float* gamma = (const float*)d_in[1];
  const float* beta  = (const float*)d_in[2];
  const float* Wq    = (const float*)d_in[3];
  const float* bq    = (const float*)d_in[4];
  const float* Wk    = (const float*)d_in[5];
  const float* bk    = (const float*)d_in[6];
  const float* Wv    = (const float*)d_in[7];
  const float* bv    = (const float*)d_in[8];
  const float* Wp    = (const float*)d_in[9];
  const float* bp    = (const float*)d_in[10];
  float* out = (float*)d_out;

  char* ws = (char*)d_ws;
  size_t off = 0;
  auto alloc = [&](size_t bytes) -> void* {
    void* p = ws + off;
    off += (bytes + 255) & ~(size_t)255;
    return p;
  };
  const size_t X8 = (size_t)TOKENS * CH;        // 8 MB fp8
  const size_t X4 = (size_t)TOKENS * CH / 2;    // 4 MB fp4
  const size_t W8 = (size_t)CH * CH;            // 0.25 MB fp8

  float2* stats = (float2*)alloc(128 * sizeof(float2));
  u8* xn8   = (u8*)alloc(X8);    // fp8 normalized input
  u8* O8    = (u8*)alloc(X8);    // fp8 attention out
  u8* Q4    = (u8*)alloc(X4);    // fp4 (x4 pre-scaled), kappa-c channel order
  u8* K4    = (u8*)alloc(X4);
  u8* V4    = (u8*)alloc(X4);    // fp4 [B][CH][HW/2]
  u8* Wqkv8 = (u8*)alloc(3 * W8);
  u8* Wp8   = (u8*)alloc(W8);

  gn_stats<<<128, 256, 0, stream>>>(x, stats);
  gn_apply8<<<TOKENS * CH / 8 / 256, 256, 0, stream>>>(x, gamma, beta, stats, xn8);
  transpose_w8<<<dim3(16, 16, 4), dim3(32, 8), 0, stream>>>(
      Wq, Wk, Wv, Wp, Wqkv8, Wqkv8 + (size_t)CH * CH, Wqkv8 + 2 * (size_t)CH * CH, Wp8);

  qkvmx<<<dim3(1536 / 128, TOKENS / 128), 256, 0, stream>>>(
      xn8, Wqkv8, bq, bk, bv, Q4, K4, V4);

  const float scl = 0.044194173824159216f;  // 1/sqrt(512)
  flash32<<<dim3(512), 512, 0, stream>>>(Q4, K4, V4, O8, scl);

  projmx<<<dim3(4, TOKENS / 128), 256, 0, stream>>>(O8, Wp8, bp, x, out);
}

// Round 17
// 160.038 us; speedup vs baseline: 1.1713x; 1.1713x over previous
//
#include <hip/hip_runtime.h>

typedef unsigned short u16;
typedef unsigned char u8;
typedef float f32x4 __attribute__((ext_vector_type(4)));
typedef int i32x8 __attribute__((ext_vector_type(8)));

#define CH 512
#define HW 4096
#define TOKENS 16384
#define NGRP 32

__device__ __forceinline__ u8 f2fp8(float f) {   // OCP e4m3fn, RNE+sat
  return (u8)(__builtin_amdgcn_cvt_pk_fp8_f32(f, f, 0, false) & 0xff);
}
__device__ __forceinline__ unsigned f2fp8x4(float a, float b, float c, float d) {
  int lo = __builtin_amdgcn_cvt_pk_fp8_f32(a, b, 0, false);
  return (unsigned)__builtin_amdgcn_cvt_pk_fp8_f32(c, d, lo, true);
}
// fp4 e2m1 encode of 4*x (pre-scale x4; MFMA dequants with E8M0 scale 125 = 2^-2).
__device__ __forceinline__ unsigned nib4(float x) {
  float a = fabsf(x) * 4.0f;
  unsigned c = (unsigned)(a >= 0.25f) + (a >= 0.75f) + (a >= 1.25f) + (a >= 1.75f) +
               (a >= 2.5f) + (a >= 3.5f) + (a >= 5.0f);
  return c | ((__float_as_uint(x) >> 28) & 8u);
}
__device__ __forceinline__ u16 pk4(float a, float b, float c, float d) {
  return (u16)(nib4(a) | (nib4(b) << 4) | (nib4(c) << 8) | (nib4(d) << 12));
}

// async global->LDS, 16B per lane
#define GLOAD16(gp, lp)                                                        \
  __builtin_amdgcn_global_load_lds(                                            \
      (const __attribute__((address_space(1))) unsigned int*)(const void*)(gp),\
      (__attribute__((address_space(3))) unsigned int*)(void*)(lp), 16, 0, 0)

// fp8 frag read: 32B at swizzled offset (rows 128B, granule ^= row&7)
#define RD8(dst, buf, row) do {                                                \
    int base_ = (row) * 128, sw_ = ((row) & 7) << 4;                           \
    uint4 lo_ = *(const uint4*)(&buf[base_ + ((h * 32) ^ sw_)]);               \
    uint4 hi_ = *(const uint4*)(&buf[base_ + ((h * 32 + 16) ^ sw_)]);          \
    dst[0] = (int)lo_.x; dst[1] = (int)lo_.y; dst[2] = (int)lo_.z;             \
    dst[3] = (int)lo_.w; dst[4] = (int)hi_.x; dst[5] = (int)hi_.y;             \
    dst[6] = (int)hi_.z; dst[7] = (int)hi_.w;                                  \
  } while (0)

// fp4 frag read, 256B rows: 16B at swizzled offset (granule ^= row&7)
#define RD4W(dst, buf, row, ks) do {                                           \
    uint4 t_ = *(const uint4*)(&buf[(row) * 256 +                              \
                                    (((ks) * 64 + h * 16) ^ (((row) & 7) << 4))]); \
    dst[0] = (int)t_.x; dst[1] = (int)t_.y; dst[2] = (int)t_.z;                \
    dst[3] = (int)t_.w; dst[4] = 0; dst[5] = 0; dst[6] = 0; dst[7] = 0;        \
  } while (0)

// fp4 frag read, 64B rows: 16B at swizzled offset (granule ^= row&3)
#define RD4(dst, buf, row) do {                                                \
    uint4 t_ = *(const uint4*)(&buf[(row) * 64 + ((h * 16) ^ (((row) & 3) << 4))]); \
    dst[0] = (int)t_.x; dst[1] = (int)t_.y; dst[2] = (int)t_.z;                \
    dst[3] = (int)t_.w; dst[4] = 0; dst[5] = 0; dst[6] = 0; dst[7] = 0;        \
  } while (0)

// ---------------- GroupNorm stats: one block per (b,g) ----------------
__global__ void gn_stats(const float* __restrict__ x, float2* __restrict__ stats) {
  int bg = blockIdx.x;              // 0..127
  int b = bg >> 5, g = bg & 31;
  const float* base = x + (size_t)b * HW * CH + g * 16;
  float s = 0.f, s2 = 0.f;
  for (int p = threadIdx.x; p < HW; p += 256) {
    const float4* row = (const float4*)(base + (size_t)p * CH);
#pragma unroll
    for (int q = 0; q < 4; ++q) {
      float4 v = row[q];
      s += v.x + v.y + v.z + v.w;
      s2 += v.x * v.x + v.y * v.y + v.z * v.z + v.w * v.w;
    }
  }
#pragma unroll
  for (int o = 32; o; o >>= 1) { s += __shfl_down(s, o); s2 += __shfl_down(s2, o); }
  __shared__ float rs[4], rs2[4];
  int wid = threadIdx.x >> 6, lane = threadIdx.x & 63;
  if (lane == 0) { rs[wid] = s; rs2[wid] = s2; }
  __syncthreads();
  if (threadIdx.x == 0) {
    float S = rs[0] + rs[1] + rs[2] + rs[3];
    float S2 = rs2[0] + rs2[1] + rs2[2] + rs2[3];
    float mean = S * (1.f / 65536.f);
    float var = S2 * (1.f / 65536.f) - mean * mean;
    stats[bg] = make_float2(mean, rsqrtf(var + 1e-5f));
  }
}

// ---------------- GroupNorm apply -> xn8 (fp8) ----------------
__global__ void gn_apply8(const float* __restrict__ x, const float* __restrict__ gamma,
                          const float* __restrict__ beta, const float2* __restrict__ stats,
                          u8* __restrict__ xn8) {
  size_t i = (size_t)blockIdx.x * blockDim.x + threadIdx.x;  // chunk of 8 elems
  size_t e0 = i * 8;
  int c = (int)(e0 & (CH - 1));
  size_t t = e0 >> 9;
  int b = (int)(t >> 12);
  float2 st = stats[b * NGRP + (c >> 4)];
  float4 v0 = *(const float4*)(x + t * CH + c);
  float4 v1 = *(const float4*)(x + t * CH + c + 4);
  float4 g0 = *(const float4*)(gamma + c);
  float4 g1 = *(const float4*)(gamma + c + 4);
  float4 b0 = *(const float4*)(beta + c);
  float4 b1 = *(const float4*)(beta + c + 4);
  float o[8];
  o[0] = (v0.x - st.x) * st.y * g0.x + b0.x;
  o[1] = (v0.y - st.x) * st.y * g0.y + b0.y;
  o[2] = (v0.z - st.x) * st.y * g0.z + b0.z;
  o[3] = (v0.w - st.x) * st.y * g0.w + b0.w;
  o[4] = (v1.x - st.x) * st.y * g1.x + b1.x;
  o[5] = (v1.y - st.x) * st.y * g1.y + b1.y;
  o[6] = (v1.z - st.x) * st.y * g1.z + b1.z;
  o[7] = (v1.w - st.x) * st.y * g1.w + b1.w;
  uint2 pk;
  pk.x = f2fp8x4(o[0], o[1], o[2], o[3]);
  pk.y = f2fp8x4(o[4], o[5], o[6], o[7]);
  *(uint2*)(xn8 + e0) = pk;
}

// ---------------- transpose 512x512 weights fp32 -> fp8 (T[d][c] = W[c][d]) ----------------
__global__ void transpose_w8(const float* __restrict__ W0, const float* __restrict__ W1,
                             const float* __restrict__ W2, const float* __restrict__ W3,
                             u8* __restrict__ T0, u8* __restrict__ T1,
                             u8* __restrict__ T2, u8* __restrict__ T3) {
  const float* W; u8* T;
  switch (blockIdx.z) {
    case 0: W = W0; T = T0; break;
    case 1: W = W1; T = T1; break;
    case 2: W = W2; T = T2; break;
    default: W = W3; T = T3; break;
  }
  __shared__ float tile[32][33];
  int tx = threadIdx.x, ty = threadIdx.y;
  int x0 = blockIdx.x * 32, y0 = blockIdx.y * 32;
#pragma unroll
  for (int r = 0; r < 32; r += 8) tile[ty + r][tx] = W[(size_t)(y0 + ty + r) * CH + x0 + tx];
  __syncthreads();
#pragma unroll
  for (int r = 0; r < 32; r += 8) T[(size_t)(x0 + ty + r) * CH + y0 + tx] = f2fp8(tile[tx][ty + r]);
}

// ---- QKV: MX-fp8 GEMM (xn8 x Wqkv8), epilogue -> fp4 Q4,K4 (kappa-c packed) + fp4 V4t ----
__global__ __launch_bounds__(256) void qkvmx(const u8* __restrict__ A,
                                             const u8* __restrict__ Bt,
                                             const float* __restrict__ bq,
                                             const float* __restrict__ bk,
                                             const float* __restrict__ bv,
                                             u8* __restrict__ Q4, u8* __restrict__ K4,
                                             u8* __restrict__ V4) {
  constexpr int BK = 128;
  const int K = CH;
  __shared__ __align__(16) u8 lA[128 * BK];
  __shared__ __align__(16) u8 lB[128 * BK];
  const int bm = blockIdx.y * 128, bn = blockIdx.x * 128;
  const int tid = threadIdx.x, lane = tid & 63, wid = tid >> 6;
  const int wm = (wid >> 1) * 64, wn = (wid & 1) * 64;
  const int r0 = lane & 15, h = lane >> 4;

  const int srow = lane >> 3;
  const int scol = ((lane & 7) * 16) ^ ((srow & 7) << 4);
  size_t aoff[4], boff[4];
#pragma unroll
  for (int s = 0; s < 4; ++s) {
    int row = wid * 32 + s * 8 + srow;
    aoff[s] = (size_t)(bm + row) * K + scol;
    boff[s] = (size_t)(bn + row) * K + scol;
  }

  f32x4 acc[4][4] = {};
  for (int kt = 0; kt < K; kt += BK) {
    __syncthreads();
#pragma unroll
    for (int s = 0; s < 4; ++s) {
      GLOAD16(A + aoff[s] + kt, &lA[(wid * 4 + s) * 1024]);
      GLOAD16(Bt + boff[s] + kt, &lB[(wid * 4 + s) * 1024]);
    }
    __syncthreads();
    i32x8 bf[4];
#pragma unroll
    for (int j = 0; j < 4; ++j) RD8(bf[j], lB, wn + j * 16 + r0);
#pragma unroll
    for (int i = 0; i < 4; ++i) {
      i32x8 af;
      RD8(af, lA, wm + i * 16 + r0);
#pragma unroll
      for (int j = 0; j < 4; ++j)
        acc[i][j] = __builtin_amdgcn_mfma_scale_f32_16x16x128_f8f6f4(
            af, bf[j], acc[i][j], 0, 0, 0, 127, 0, 127);
    }
  }

  // epilogue: D layout col(n)=lane&15, row=(lane>>4)*4+r; chunk uniform per (block, wn)
  const int chn = (bn + wn) >> 9;
  const int nb = (bn + wn) & 511;
  if (chn == 2) {                     // V: fp4, [bb][CH][HW/2], keys 4-consecutive -> u16
#pragma unroll
    for (int j = 0; j < 4; ++j) {
      int nn = nb + j * 16 + r0;
      float bvv = bv[nn];
#pragma unroll
      for (int i = 0; i < 4; ++i) {
        int m0 = bm + wm + i * 16 + h * 4;
        int bb = m0 >> 12, tl = m0 & (HW - 1);
        *(u16*)(V4 + ((size_t)bb * CH + nn) * (HW / 2) + (tl >> 1)) =
            pk4(acc[i][j][0] + bvv, acc[i][j][1] + bvv,
                acc[i][j][2] + bvv, acc[i][j][3] + bvv);
      }
    }
  } else {                            // Q/K: fp4, rows 256B, kappa-c packed u16
    u8* P4 = chn == 0 ? Q4 : K4;
    const float* bb_ = chn == 0 ? bq : bk;
    float bj[4];
#pragma unroll
    for (int j = 0; j < 4; ++j) bj[j] = bb_[nb + j * 16 + r0];
#pragma unroll
    for (int i = 0; i < 4; ++i) {
#pragma unroll
      for (int r = 0; r < 4; ++r) {
        int m0r = bm + wm + i * 16 + h * 4 + r;
        *(u16*)(P4 + (size_t)m0r * 256 + (nb >> 1) + 2 * r0) =
            pk4(acc[i][0][r] + bj[0], acc[i][1][r] + bj[1],
                acc[i][2][r] + bj[2], acc[i][3][r] + bj[3]);
      }
    }
  }
}

// ---- S-GEMM MX-fp4, FULL-K staging: whole 256B-row panels (A,B) staged once ----
// LDS 64 KB (2 blocks/CU); ONE stage+drain+barrier, then 64 MFMAs/wave unbroken.
// Swizzle: granule ^= (row&7), both sides (write via pre-swizzled source col;
// s-chunk adds 16 rows so (row&7) is chunk-invariant).
__global__ __launch_bounds__(256) void sgemm4(const u8* __restrict__ Q4,
                                              const u8* __restrict__ K4,
                                              float* __restrict__ lsum,
                                              u8* __restrict__ S8,
                                              float scale,
                                              size_t sA, size_t sB, size_t sC) {
  __shared__ __align__(16) u8 lA[128 * 256];   // 32 KB
  __shared__ __align__(16) u8 lB[128 * 256];   // 32 KB
  const int z = blockIdx.z;
  const u8* A = Q4 + (size_t)z * sA;
  const u8* B = K4 + (size_t)z * sB;
  const int bm = blockIdx.y * 128, bn = blockIdx.x * 128;
  const int tid = threadIdx.x, lane = tid & 63, wid = tid >> 6;
  const int wm = (wid >> 1) * 64, wn = (wid & 1) * 64;
  const int r0 = lane & 15, h = lane >> 4;

  // staging: thread t covers 16B at LDS linear (t*16 + s*4096); dest row = (t>>4)+s*16
  const int drow = tid >> 4;
  const int scol = ((tid & 15) ^ (drow & 7)) * 16;
  const size_t aoff = (size_t)(bm + drow) * 256 + scol;
  const size_t boff = (size_t)(bn + drow) * 256 + scol;
#pragma unroll
  for (int s = 0; s < 8; ++s) {
    GLOAD16(A + aoff + (size_t)s * 4096, &lA[wid * 1024 + s * 4096]);
    GLOAD16(B + boff + (size_t)s * 4096, &lB[wid * 1024 + s * 4096]);
  }
  __syncthreads();

  f32x4 acc[4][4] = {};
#pragma unroll
  for (int ks = 0; ks < 4; ++ks) {
    i32x8 bf[4];
#pragma unroll
    for (int j = 0; j < 4; ++j) RD4W(bf[j], lB, wn + j * 16 + r0, ks);
#pragma unroll
    for (int i = 0; i < 4; ++i) {
      i32x8 af;
      RD4W(af, lA, wm + i * 16 + r0, ks);
#pragma unroll
      for (int j = 0; j < 4; ++j)
        acc[i][j] = __builtin_amdgcn_mfma_scale_f32_16x16x128_f8f6f4(
            af, bf[j], acc[i][j], 4, 4, 0, 125, 0, 125);
    }
  }

  // epilogue: exp + fp8 store + partial rowsums (R13-proven)
  u8* C = S8 + (size_t)z * sC;
  float* lp = lsum + (size_t)(z * 64 + blockIdx.x * 2 + (wid & 1)) * HW;
#pragma unroll
  for (int i = 0; i < 4; ++i) {
    int m0 = bm + wm + i * 16 + h * 4;
    float rs[4] = {0.f, 0.f, 0.f, 0.f};
#pragma unroll
    for (int j = 0; j < 4; ++j) {
      int n = bn + wn + j * 16 + r0;
#pragma unroll
      for (int r = 0; r < 4; ++r) {
        float e = __expf(acc[i][j][r] * scale);
        rs[r] += e;
        C[(size_t)(m0 + r) * HW + n] = f2fp8(e);
      }
    }
#pragma unroll
    for (int r = 0; r < 4; ++r) {
#pragma unroll
      for (int w = 1; w < 16; w <<= 1) rs[r] += __shfl_xor(rs[r], w);
      if (r0 == 0) lp[m0 + r] = rs[r];
    }
  }
}

// ---- PV mixed fp8xfp4: O8 = fp8((S8 V4^T)/rowsum); XCD-swizzled when gridDim.y==1 ----
__global__ __launch_bounds__(256) void pv84(const u8* __restrict__ S8,
                                            const u8* __restrict__ V4,
                                            const float* __restrict__ lsum_in,
                                            u8* __restrict__ O8) {
  __shared__ __align__(16) u8 lA[128 * 128];  // S fp8 tile 16 KB
  __shared__ __align__(16) u8 lB[128 * 64];   // V fp4 tile  8 KB
  __shared__ float lsum_sh[128];

  int bm, bn, z;
  if (gridDim.y == 1) {               // big path: 512 blocks, XCD-chunked swizzle
    int p = blockIdx.x;
    int xcd = p & 7, j = p >> 3;
    int xi = j & 3;
    int mp = xcd * 16 + (j >> 2);
    bn = xi * 128; bm = (mp & 31) * 128; z = mp >> 5;
  } else {
    z = blockIdx.z; bm = blockIdx.y * 128; bn = blockIdx.x * 128;
  }
  const u8* A = S8 + (size_t)z * HW * HW;
  const u8* B = V4 + (size_t)z * CH * (HW / 2);
  const float* lsum = lsum_in + (size_t)z * 64 * HW;
  u8* C = O8 + (size_t)z * HW * CH;

  const int tid = threadIdx.x, lane = tid & 63, wid = tid >> 6;
  const int wm = (wid >> 1) * 64, wn = (wid & 1) * 64;
  const int r0 = lane & 15, h = lane >> 4;

  if (tid < 128) {
    const float* lp = lsum + bm + tid;
    float s = 0.f;
#pragma unroll 8
    for (int p = 0; p < 64; ++p) s += lp[(size_t)p * HW];
    lsum_sh[tid] = s;
  }

  // A staging: fp8, rows 4096B global stride, tile rows 128B, swizzle granule ^= row&7
  const int srow8 = lane >> 3;
  const int scol8 = ((lane & 7) * 16) ^ ((srow8 & 7) << 4);
  size_t aoff[4];
#pragma unroll
  for (int s = 0; s < 4; ++s)
    aoff[s] = (size_t)(bm + wid * 32 + s * 8 + srow8) * HW + scol8;
  // B staging: fp4, rows 2048B global stride, tile rows 64B, swizzle granule ^= row&3
  const int srow4 = lane >> 2;
  const int scol4 = (((lane & 3) ^ (srow4 & 3)) << 4);
  size_t boff[2];
#pragma unroll
  for (int s = 0; s < 2; ++s)
    boff[s] = (size_t)(bn + wid * 32 + s * 16 + srow4) * (HW / 2) + scol4;

  f32x4 acc[4][4] = {};
  for (int kt = 0; kt < HW; kt += 128) {     // 32 K-steps
    __syncthreads();
#pragma unroll
    for (int s = 0; s < 4; ++s) GLOAD16(A + aoff[s] + kt, &lA[(wid * 4 + s) * 1024]);
#pragma unroll
    for (int s = 0; s < 2; ++s) GLOAD16(B + boff[s] + (kt >> 1), &lB[(wid * 2 + s) * 1024]);
    __syncthreads();
    i32x8 bf[4];
#pragma unroll
    for (int j = 0; j < 4; ++j) RD4(bf[j], lB, wn + j * 16 + r0);
#pragma unroll
    for (int i = 0; i < 4; ++i) {
      i32x8 af;
      RD8(af, lA, wm + i * 16 + r0);
#pragma unroll
      for (int j = 0; j < 4; ++j)
        acc[i][j] = __builtin_amdgcn_mfma_scale_f32_16x16x128_f8f6f4(
            af, bf[j], acc[i][j], 0, 4, 0, 127, 0, 125);
    }
  }

  // epilogue: divide by rowsum, fp8 out
#pragma unroll
  for (int j = 0; j < 4; ++j) {
    int n = bn + wn + j * 16 + r0;
#pragma unroll
    for (int i = 0; i < 4; ++i) {
      int m0 = bm + wm + i * 16 + h * 4;
#pragma unroll
      for (int r = 0; r < 4; ++r) {
        float inv = 1.0f / lsum_sh[wm + i * 16 + h * 4 + r];
        C[(size_t)(m0 + r) * CH + n] = f2fp8(acc[i][j][r] * inv);
      }
    }
  }
}

// ---- proj: MX-fp8 GEMM (O8 x Wp8), f32 out + bias + residual ----
__global__ __launch_bounds__(256) void projmx(const u8* __restrict__ A,
                                              const u8* __restrict__ Bt,
                                              const float* __restrict__ bias,
                                              const float* __restrict__ residual,
                                              float* __restrict__ Cout) {
  constexpr int BK = 128;
  const int K = CH, N = CH;
  __shared__ __align__(16) u8 lA[128 * BK];
  __shared__ __align__(16) u8 lB[128 * BK];
  const int bm = blockIdx.y * 128, bn = blockIdx.x * 128;
  const int tid = threadIdx.x, lane = tid & 63, wid = tid >> 6;
  const int wm = (wid >> 1) * 64, wn = (wid & 1) * 64;
  const int r0 = lane & 15, h = lane >> 4;

  const int srow = lane >> 3;
  const int scol = ((lane & 7) * 16) ^ ((srow & 7) << 4);
  size_t aoff[4], boff[4];
#pragma unroll
  for (int s = 0; s < 4; ++s) {
    int row = wid * 32 + s * 8 + srow;
    aoff[s] = (size_t)(bm + row) * K + scol;
    boff[s] = (size_t)(bn + row) * K + scol;
  }

  f32x4 acc[4][4] = {};
  for (int kt = 0; kt < K; kt += BK) {
    __syncthreads();
#pragma unroll
    for (int s = 0; s < 4; ++s) {
      GLOAD16(A + aoff[s] + kt, &lA[(wid * 4 + s) * 1024]);
      GLOAD16(Bt + boff[s] + kt, &lB[(wid * 4 + s) * 1024]);
    }
    __syncthreads();
    i32x8 bf[4];
#pragma unroll
    for (int j = 0; j < 4; ++j) RD8(bf[j], lB, wn + j * 16 + r0);
#pragma unroll
    for (int i = 0; i < 4; ++i) {
      i32x8 af;
      RD8(af, lA, wm + i * 16 + r0);
#pragma unroll
      for (int j = 0; j < 4; ++j)
        acc[i][j] = __builtin_amdgcn_mfma_scale_f32_16x16x128_f8f6f4(
            af, bf[j], acc[i][j], 0, 0, 0, 127, 0, 127);
    }
  }

#pragma unroll
  for (int j = 0; j < 4; ++j) {
    int n = bn + wn + j * 16 + r0;
    float bvv = bias[n];
#pragma unroll
    for (int i = 0; i < 4; ++i) {
      int m0 = bm + wm + i * 16 + h * 4;
#pragma unroll
      for (int r = 0; r < 4; ++r) {
        size_t idx = (size_t)(m0 + r) * N + n;
        Cout[idx] = acc[i][j][r] + bvv + residual[idx];
      }
    }
  }
}

extern "C" void kernel_launch(void* const* d_in, const int* in_sizes, int n_in,
                              void* d_out, int out_size, void* d_ws, size_t ws_size,
                              hipStream_t stream) {
  (void)in_sizes; (void)n_in; (void)out_size;
  const float* x     = (const float*)d_in[0];
  const float* gamma = (const float*)d_in[1];
  const float* beta  = (const float*)d_in[2];
  const float* Wq    = (const float*)d_in[3];
  const float* bq    = (const float*)d_in[4];
  const float* Wk    = (const float*)d_in[5];
  const float* bk    = (const float*)d_in[6];
  const float* Wv    = (const float*)d_in[7];
  const float* bv    = (const float*)d_in[8];
  const float* Wp    = (const float*)d_in[9];
  const float* bp    = (const float*)d_in[10];
  float* out = (float*)d_out;

  char* ws = (char*)d_ws;
  size_t off = 0;
  auto alloc = [&](size_t bytes) -> void* {
    void* p = ws + off;
    off += (bytes + 255) & ~(size_t)255;
    return p;
  };
  const size_t X8  = (size_t)TOKENS * CH;         // 8 MB fp8
  const size_t X4  = (size_t)TOKENS * CH / 2;     // 4 MB fp4
  const size_t W8  = (size_t)CH * CH;             // 0.25 MB fp8
  const size_t S8B = (size_t)HW * HW;             // 16.8 MB fp8 per batch
  const size_t LS  = (size_t)4 * 64 * HW * sizeof(float);  // 4 MB partial rowsums
  const size_t need_all = 1024 * 1024 + LS + 2 * X8 + 3 * X4 + 4 * W8 + 4 * S8B;
  const bool big = ws_size >= need_all;           // deterministic across calls

  float2* stats    = (float2*)alloc(128 * sizeof(float2));
  float* lsum_part = (float*)alloc(LS);           // [z][64][HW]
  u8* xn8   = (u8*)alloc(X8);    // fp8 normalized input
  u8* O8    = (u8*)alloc(X8);    // fp8 attention out
  u8* Q4    = (u8*)alloc(X4);    // fp4 (x4 pre-scaled), kappa-c channel order
  u8* K4    = (u8*)alloc(X4);
  u8* V4    = (u8*)alloc(X4);    // fp4 [B][CH][HW/2]
  u8* Wqkv8 = (u8*)alloc(3 * W8);
  u8* Wp8   = (u8*)alloc(W8);
  u8* S8    = (u8*)alloc(big ? 4 * S8B : S8B);

  gn_stats<<<128, 256, 0, stream>>>(x, stats);
  gn_apply8<<<TOKENS * CH / 8 / 256, 256, 0, stream>>>(x, gamma, beta, stats, xn8);
  transpose_w8<<<dim3(16, 16, 4), dim3(32, 8), 0, stream>>>(
      Wq, Wk, Wv, Wp, Wqkv8, Wqkv8 + (size_t)CH * CH, Wqkv8 + 2 * (size_t)CH * CH, Wp8);

  qkvmx<<<dim3(1536 / 128, TOKENS / 128), 256, 0, stream>>>(
      xn8, Wqkv8, bq, bk, bv, Q4, K4, V4);

  const float scl = 0.044194173824159216f;  // 1/sqrt(512)
  const size_t sQ = (size_t)HW * 256;       // fp4 row = 256 B
  if (big) {
    sgemm4<<<dim3(32, 32, 4), 256, 0, stream>>>(
        Q4, K4, lsum_part, S8, scl, sQ, sQ, (size_t)HW * HW);
    pv84<<<dim3(512, 1, 1), 256, 0, stream>>>(S8, V4, lsum_part, O8);
  } else {
    for (int b = 0; b < 4; ++b) {
      sgemm4<<<dim3(32, 32, 1), 256, 0, stream>>>(
          Q4 + (size_t)b * sQ, K4 + (size_t)b * sQ,
          lsum_part + (size_t)b * 64 * HW, S8, scl, 0, 0, 0);
      pv84<<<dim3(4, 32, 1), 256, 0, stream>>>(
          S8, V4 + (size_t)b * CH * (HW / 2),
          lsum_part + (size_t)b * 64 * HW, O8 + (size_t)b * HW * CH);
    }
  }

  projmx<<<dim3(4, TOKENS / 128), 256, 0, stream>>>(O8, Wp8, bp, x, out);
}

// Round 18
// 157.542 us; speedup vs baseline: 1.1898x; 1.0158x over previous
//
#include <hip/hip_runtime.h>

typedef unsigned short u16;
typedef unsigned char u8;
typedef float f32x4 __attribute__((ext_vector_type(4)));
typedef int i32x8 __attribute__((ext_vector_type(8)));

#define CH 512
#define HW 4096
#define TOKENS 16384
#define NGRP 32

__device__ __forceinline__ u8 f2fp8(float f) {   // OCP e4m3fn, RNE+sat
  return (u8)(__builtin_amdgcn_cvt_pk_fp8_f32(f, f, 0, false) & 0xff);
}
__device__ __forceinline__ unsigned f2fp8x4(float a, float b, float c, float d) {
  int lo = __builtin_amdgcn_cvt_pk_fp8_f32(a, b, 0, false);
  return (unsigned)__builtin_amdgcn_cvt_pk_fp8_f32(c, d, lo, true);
}
// fp4 e2m1 encode of 4*x (pre-scale x4; MFMA dequants with E8M0 scale 125 = 2^-2).
__device__ __forceinline__ unsigned nib4(float x) {
  float a = fabsf(x) * 4.0f;
  unsigned c = (unsigned)(a >= 0.25f) + (a >= 0.75f) + (a >= 1.25f) + (a >= 1.75f) +
               (a >= 2.5f) + (a >= 3.5f) + (a >= 5.0f);
  return c | ((__float_as_uint(x) >> 28) & 8u);
}
__device__ __forceinline__ u16 pk4(float a, float b, float c, float d) {
  return (u16)(nib4(a) | (nib4(b) << 4) | (nib4(c) << 8) | (nib4(d) << 12));
}

// async global->LDS, 16B per lane
#define GLOAD16(gp, lp)                                                        \
  __builtin_amdgcn_global_load_lds(                                            \
      (const __attribute__((address_space(1))) unsigned int*)(const void*)(gp),\
      (__attribute__((address_space(3))) unsigned int*)(void*)(lp), 16, 0, 0)

// fp8 frag read: 32B at swizzled offset (rows 128B, granule ^= row&7)
#define RD8(dst, buf, row) do {                                                \
    int base_ = (row) * 128, sw_ = ((row) & 7) << 4;                           \
    uint4 lo_ = *(const uint4*)(&buf[base_ + ((h * 32) ^ sw_)]);               \
    uint4 hi_ = *(const uint4*)(&buf[base_ + ((h * 32 + 16) ^ sw_)]);          \
    dst[0] = (int)lo_.x; dst[1] = (int)lo_.y; dst[2] = (int)lo_.z;             \
    dst[3] = (int)lo_.w; dst[4] = (int)hi_.x; dst[5] = (int)hi_.y;             \
    dst[6] = (int)hi_.z; dst[7] = (int)hi_.w;                                  \
  } while (0)

// fp4 frag read, 256B rows: 16B at swizzled offset (granule ^= row&7)
#define RD4W(dst, buf, row, ks) do {                                           \
    uint4 t_ = *(const uint4*)(&buf[(row) * 256 +                              \
                                    (((ks) * 64 + h * 16) ^ (((row) & 7) << 4))]); \
    dst[0] = (int)t_.x; dst[1] = (int)t_.y; dst[2] = (int)t_.z;                \
    dst[3] = (int)t_.w; dst[4] = 0; dst[5] = 0; dst[6] = 0; dst[7] = 0;        \
  } while (0)

// fp4 frag read, 64B rows: 16B at swizzled offset (granule ^= row&3)
#define RD4(dst, buf, row) do {                                                \
    uint4 t_ = *(const uint4*)(&buf[(row) * 64 + ((h * 16) ^ (((row) & 3) << 4))]); \
    dst[0] = (int)t_.x; dst[1] = (int)t_.y; dst[2] = (int)t_.z;                \
    dst[3] = (int)t_.w; dst[4] = 0; dst[5] = 0; dst[6] = 0; dst[7] = 0;        \
  } while (0)

// ---------------- GroupNorm stats: one block per (b,g) ----------------
__global__ void gn_stats(const float* __restrict__ x, float2* __restrict__ stats) {
  int bg = blockIdx.x;              // 0..127
  int b = bg >> 5, g = bg & 31;
  const float* base = x + (size_t)b * HW * CH + g * 16;
  float s = 0.f, s2 = 0.f;
  for (int p = threadIdx.x; p < HW; p += 256) {
    const float4* row = (const float4*)(base + (size_t)p * CH);
#pragma unroll
    for (int q = 0; q < 4; ++q) {
      float4 v = row[q];
      s += v.x + v.y + v.z + v.w;
      s2 += v.x * v.x + v.y * v.y + v.z * v.z + v.w * v.w;
    }
  }
#pragma unroll
  for (int o = 32; o; o >>= 1) { s += __shfl_down(s, o); s2 += __shfl_down(s2, o); }
  __shared__ float rs[4], rs2[4];
  int wid = threadIdx.x >> 6, lane = threadIdx.x & 63;
  if (lane == 0) { rs[wid] = s; rs2[wid] = s2; }
  __syncthreads();
  if (threadIdx.x == 0) {
    float S = rs[0] + rs[1] + rs[2] + rs[3];
    float S2 = rs2[0] + rs2[1] + rs2[2] + rs2[3];
    float mean = S * (1.f / 65536.f);
    float var = S2 * (1.f / 65536.f) - mean * mean;
    stats[bg] = make_float2(mean, rsqrtf(var + 1e-5f));
  }
}

// ---------------- GroupNorm apply -> xn8 (fp8) ----------------
__global__ void gn_apply8(const float* __restrict__ x, const float* __restrict__ gamma,
                          const float* __restrict__ beta, const float2* __restrict__ stats,
                          u8* __restrict__ xn8) {
  size_t i = (size_t)blockIdx.x * blockDim.x + threadIdx.x;  // chunk of 8 elems
  size_t e0 = i * 8;
  int c = (int)(e0 & (CH - 1));
  size_t t = e0 >> 9;
  int b = (int)(t >> 12);
  float2 st = stats[b * NGRP + (c >> 4)];
  float4 v0 = *(const float4*)(x + t * CH + c);
  float4 v1 = *(const float4*)(x + t * CH + c + 4);
  float4 g0 = *(const float4*)(gamma + c);
  float4 g1 = *(const float4*)(gamma + c + 4);
  float4 b0 = *(const float4*)(beta + c);
  float4 b1 = *(const float4*)(beta + c + 4);
  float o[8];
  o[0] = (v0.x - st.x) * st.y * g0.x + b0.x;
  o[1] = (v0.y - st.x) * st.y * g0.y + b0.y;
  o[2] = (v0.z - st.x) * st.y * g0.z + b0.z;
  o[3] = (v0.w - st.x) * st.y * g0.w + b0.w;
  o[4] = (v1.x - st.x) * st.y * g1.x + b1.x;
  o[5] = (v1.y - st.x) * st.y * g1.y + b1.y;
  o[6] = (v1.z - st.x) * st.y * g1.z + b1.z;
  o[7] = (v1.w - st.x) * st.y * g1.w + b1.w;
  uint2 pk;
  pk.x = f2fp8x4(o[0], o[1], o[2], o[3]);
  pk.y = f2fp8x4(o[4], o[5], o[6], o[7]);
  *(uint2*)(xn8 + e0) = pk;
}

// ---------------- transpose 512x512 weights fp32 -> fp8 (T[d][c] = W[c][d]) ----------------
__global__ void transpose_w8(const float* __restrict__ W0, const float* __restrict__ W1,
                             const float* __restrict__ W2, const float* __restrict__ W3,
                             u8* __restrict__ T0, u8* __restrict__ T1,
                             u8* __restrict__ T2, u8* __restrict__ T3) {
  const float* W; u8* T;
  switch (blockIdx.z) {
    case 0: W = W0; T = T0; break;
    case 1: W = W1; T = T1; break;
    case 2: W = W2; T = T2; break;
    default: W = W3; T = T3; break;
  }
  __shared__ float tile[32][33];
  int tx = threadIdx.x, ty = threadIdx.y;
  int x0 = blockIdx.x * 32, y0 = blockIdx.y * 32;
#pragma unroll
  for (int r = 0; r < 32; r += 8) tile[ty + r][tx] = W[(size_t)(y0 + ty + r) * CH + x0 + tx];
  __syncthreads();
#pragma unroll
  for (int r = 0; r < 32; r += 8) T[(size_t)(x0 + ty + r) * CH + y0 + tx] = f2fp8(tile[tx][ty + r]);
}

// ---- QKV: MX-fp8 GEMM (xn8 x Wqkv8), epilogue -> fp4 Q4,K4 (kappa-c packed) + fp4 V4t ----
__global__ __launch_bounds__(256) void qkvmx(const u8* __restrict__ A,
                                             const u8* __restrict__ Bt,
                                             const float* __restrict__ bq,
                                             const float* __restrict__ bk,
                                             const float* __restrict__ bv,
                                             u8* __restrict__ Q4, u8* __restrict__ K4,
                                             u8* __restrict__ V4) {
  constexpr int BK = 128;
  const int K = CH;
  __shared__ __align__(16) u8 lA[128 * BK];
  __shared__ __align__(16) u8 lB[128 * BK];
  const int bm = blockIdx.y * 128, bn = blockIdx.x * 128;
  const int tid = threadIdx.x, lane = tid & 63, wid = tid >> 6;
  const int wm = (wid >> 1) * 64, wn = (wid & 1) * 64;
  const int r0 = lane & 15, h = lane >> 4;

  const int srow = lane >> 3;
  const int scol = ((lane & 7) * 16) ^ ((srow & 7) << 4);
  size_t aoff[4], boff[4];
#pragma unroll
  for (int s = 0; s < 4; ++s) {
    int row = wid * 32 + s * 8 + srow;
    aoff[s] = (size_t)(bm + row) * K + scol;
    boff[s] = (size_t)(bn + row) * K + scol;
  }

  f32x4 acc[4][4] = {};
  for (int kt = 0; kt < K; kt += BK) {
    __syncthreads();
#pragma unroll
    for (int s = 0; s < 4; ++s) {
      GLOAD16(A + aoff[s] + kt, &lA[(wid * 4 + s) * 1024]);
      GLOAD16(Bt + boff[s] + kt, &lB[(wid * 4 + s) * 1024]);
    }
    __syncthreads();
    i32x8 bf[4];
#pragma unroll
    for (int j = 0; j < 4; ++j) RD8(bf[j], lB, wn + j * 16 + r0);
#pragma unroll
    for (int i = 0; i < 4; ++i) {
      i32x8 af;
      RD8(af, lA, wm + i * 16 + r0);
#pragma unroll
      for (int j = 0; j < 4; ++j)
        acc[i][j] = __builtin_amdgcn_mfma_scale_f32_16x16x128_f8f6f4(
            af, bf[j], acc[i][j], 0, 0, 0, 127, 0, 127);
    }
  }

  // epilogue: D layout col(n)=lane&15, row=(lane>>4)*4+r; chunk uniform per (block, wn)
  const int chn = (bn + wn) >> 9;
  const int nb = (bn + wn) & 511;
  if (chn == 2) {                     // V: fp4, [bb][CH][HW/2], keys 4-consecutive -> u16
#pragma unroll
    for (int j = 0; j < 4; ++j) {
      int nn = nb + j * 16 + r0;
      float bvv = bv[nn];
#pragma unroll
      for (int i = 0; i < 4; ++i) {
        int m0 = bm + wm + i * 16 + h * 4;
        int bb = m0 >> 12, tl = m0 & (HW - 1);
        *(u16*)(V4 + ((size_t)bb * CH + nn) * (HW / 2) + (tl >> 1)) =
            pk4(acc[i][j][0] + bvv, acc[i][j][1] + bvv,
                acc[i][j][2] + bvv, acc[i][j][3] + bvv);
      }
    }
  } else {                            // Q/K: fp4, rows 256B, kappa-c packed u16
    u8* P4 = chn == 0 ? Q4 : K4;
    const float* bb_ = chn == 0 ? bq : bk;
    float bj[4];
#pragma unroll
    for (int j = 0; j < 4; ++j) bj[j] = bb_[nb + j * 16 + r0];
#pragma unroll
    for (int i = 0; i < 4; ++i) {
#pragma unroll
      for (int r = 0; r < 4; ++r) {
        int m0r = bm + wm + i * 16 + h * 4 + r;
        *(u16*)(P4 + (size_t)m0r * 256 + (nb >> 1) + 2 * r0) =
            pk4(acc[i][0][r] + bj[0], acc[i][1][r] + bj[1],
                acc[i][2][r] + bj[2], acc[i][3][r] + bj[3]);
      }
    }
  }
}

// ---- S-GEMM MX-fp4, SWAPPED (S^T compute): A = K-panel (keys = M), B = Q-panel (q = N).
// Full-K staging (64 KB LDS, one barrier pair). D gives lane 4 CONSECUTIVE KEYS at
// fixed q -> epilogue packs one u32 fp8 store per (i,j): 16 stores/thread (was 64).
// Output layout unchanged: S8[q][key]. Partial rowsums indexed by key-block:
// lsum[(z*64 + blockIdx.y*2 + (wid>>1))*HW + q]  (still 64 partials per q).
__global__ __launch_bounds__(256) void sgemm4(const u8* __restrict__ Kp,
                                              const u8* __restrict__ Qp,
                                              float* __restrict__ lsum,
                                              u8* __restrict__ S8,
                                              float scale,
                                              size_t sA, size_t sB, size_t sC) {
  __shared__ __align__(16) u8 lA[128 * 256];   // keys panel, 32 KB
  __shared__ __align__(16) u8 lB[128 * 256];   // q panel,    32 KB
  const int z = blockIdx.z;
  const u8* A = Kp + (size_t)z * sA;           // keys
  const u8* B = Qp + (size_t)z * sB;           // queries
  const int bm = blockIdx.y * 128;             // key block
  const int bn = blockIdx.x * 128;             // q block
  const int tid = threadIdx.x, lane = tid & 63, wid = tid >> 6;
  const int wm = (wid >> 1) * 64, wn = (wid & 1) * 64;
  const int r0 = lane & 15, h = lane >> 4;

  // staging: thread t covers 16B at LDS linear (t*16 + s*4096); dest row = (t>>4)+s*16
  const int drow = tid >> 4;
  const int scol = ((tid & 15) ^ (drow & 7)) * 16;
  const size_t aoff = (size_t)(bm + drow) * 256 + scol;
  const size_t boff = (size_t)(bn + drow) * 256 + scol;
#pragma unroll
  for (int s = 0; s < 8; ++s) {
    GLOAD16(A + aoff + (size_t)s * 4096, &lA[wid * 1024 + s * 4096]);
    GLOAD16(B + boff + (size_t)s * 4096, &lB[wid * 1024 + s * 4096]);
  }
  __syncthreads();

  f32x4 acc[4][4] = {};
#pragma unroll
  for (int ks = 0; ks < 4; ++ks) {
    i32x8 bf[4];
#pragma unroll
    for (int j = 0; j < 4; ++j) RD4W(bf[j], lB, wn + j * 16 + r0, ks);
#pragma unroll
    for (int i = 0; i < 4; ++i) {
      i32x8 af;
      RD4W(af, lA, wm + i * 16 + r0, ks);
#pragma unroll
      for (int j = 0; j < 4; ++j)
        acc[i][j] = __builtin_amdgcn_mfma_scale_f32_16x16x128_f8f6f4(
            af, bf[j], acc[i][j], 4, 4, 0, 125, 0, 125);
    }
  }

  // epilogue: lane (i,j) holds keys {bm+wm+i*16+h*4 .. +3} at q = bn+wn+j*16+r0
  u8* C = S8 + (size_t)z * sC;
  float* lp = lsum + (size_t)(z * 64 + blockIdx.y * 2 + (wid >> 1)) * HW;
  float rs[4] = {0.f, 0.f, 0.f, 0.f};          // per-j q-rowsum partials
#pragma unroll
  for (int i = 0; i < 4; ++i) {
    int key4 = bm + wm + i * 16 + h * 4;
#pragma unroll
    for (int j = 0; j < 4; ++j) {
      int q = bn + wn + j * 16 + r0;
      float e0 = __expf(acc[i][j][0] * scale);
      float e1 = __expf(acc[i][j][1] * scale);
      float e2 = __expf(acc[i][j][2] * scale);
      float e3 = __expf(acc[i][j][3] * scale);
      rs[j] += e0 + e1 + e2 + e3;
      *(unsigned*)(C + (size_t)q * HW + key4) = f2fp8x4(e0, e1, e2, e3);
    }
  }
#pragma unroll
  for (int j = 0; j < 4; ++j) {
    float v = rs[j];
    v += __shfl_xor(v, 16);
    v += __shfl_xor(v, 32);                    // sum over h: wave's 64 keys
    if (h == 0) lp[bn + wn + j * 16 + r0] = v;
  }
}

// ---- PV mixed fp8xfp4: O8 = fp8((S8 V4^T)/rowsum); XCD-swizzled when gridDim.y==1 ----
__global__ __launch_bounds__(256) void pv84(const u8* __restrict__ S8,
                                            const u8* __restrict__ V4,
                                            const float* __restrict__ lsum_in,
                                            u8* __restrict__ O8) {
  __shared__ __align__(16) u8 lA[128 * 128];  // S fp8 tile 16 KB
  __shared__ __align__(16) u8 lB[128 * 64];   // V fp4 tile  8 KB
  __shared__ float lsum_sh[128];

  int bm, bn, z;
  if (gridDim.y == 1) {               // big path: 512 blocks, XCD-chunked swizzle
    int p = blockIdx.x;
    int xcd = p & 7, j = p >> 3;
    int xi = j & 3;
    int mp = xcd * 16 + (j >> 2);
    bn = xi * 128; bm = (mp & 31) * 128; z = mp >> 5;
  } else {
    z = blockIdx.z; bm = blockIdx.y * 128; bn = blockIdx.x * 128;
  }
  const u8* A = S8 + (size_t)z * HW * HW;
  const u8* B = V4 + (size_t)z * CH * (HW / 2);
  const float* lsum = lsum_in + (size_t)z * 64 * HW;
  u8* C = O8 + (size_t)z * HW * CH;

  const int tid = threadIdx.x, lane = tid & 63, wid = tid >> 6;
  const int wm = (wid >> 1) * 64, wn = (wid & 1) * 64;
  const int r0 = lane & 15, h = lane >> 4;

  if (tid < 128) {
    const float* lp = lsum + bm + tid;
    float s = 0.f;
#pragma unroll 8
    for (int p = 0; p < 64; ++p) s += lp[(size_t)p * HW];
    lsum_sh[tid] = s;
  }

  // A staging: fp8, rows 4096B global stride, tile rows 128B, swizzle granule ^= row&7
  const int srow8 = lane >> 3;
  const int scol8 = ((lane & 7) * 16) ^ ((srow8 & 7) << 4);
  size_t aoff[4];
#pragma unroll
  for (int s = 0; s < 4; ++s)
    aoff[s] = (size_t)(bm + wid * 32 + s * 8 + srow8) * HW + scol8;
  // B staging: fp4, rows 2048B global stride, tile rows 64B, swizzle granule ^= row&3
  const int srow4 = lane >> 2;
  const int scol4 = (((lane & 3) ^ (srow4 & 3)) << 4);
  size_t boff[2];
#pragma unroll
  for (int s = 0; s < 2; ++s)
    boff[s] = (size_t)(bn + wid * 32 + s * 16 + srow4) * (HW / 2) + scol4;

  f32x4 acc[4][4] = {};
  for (int kt = 0; kt < HW; kt += 128) {     // 32 K-steps
    __syncthreads();
#pragma unroll
    for (int s = 0; s < 4; ++s) GLOAD16(A + aoff[s] + kt, &lA[(wid * 4 + s) * 1024]);
#pragma unroll
    for (int s = 0; s < 2; ++s) GLOAD16(B + boff[s] + (kt >> 1), &lB[(wid * 2 + s) * 1024]);
    __syncthreads();
    i32x8 bf[4];
#pragma unroll
    for (int j = 0; j < 4; ++j) RD4(bf[j], lB, wn + j * 16 + r0);
#pragma unroll
    for (int i = 0; i < 4; ++i) {
      i32x8 af;
      RD8(af, lA, wm + i * 16 + r0);
#pragma unroll
      for (int j = 0; j < 4; ++j)
        acc[i][j] = __builtin_amdgcn_mfma_scale_f32_16x16x128_f8f6f4(
            af, bf[j], acc[i][j], 0, 4, 0, 127, 0, 125);
    }
  }

  // epilogue: divide by rowsum, fp8 out
#pragma unroll
  for (int j = 0; j < 4; ++j) {
    int n = bn + wn + j * 16 + r0;
#pragma unroll
    for (int i = 0; i < 4; ++i) {
      int m0 = bm + wm + i * 16 + h * 4;
#pragma unroll
      for (int r = 0; r < 4; ++r) {
        float inv = 1.0f / lsum_sh[wm + i * 16 + h * 4 + r];
        C[(size_t)(m0 + r) * CH + n] = f2fp8(acc[i][j][r] * inv);
      }
    }
  }
}

// ---- proj: MX-fp8 GEMM (O8 x Wp8), f32 out + bias + residual ----
__global__ __launch_bounds__(256) void projmx(const u8* __restrict__ A,
                                              const u8* __restrict__ Bt,
                                              const float* __restrict__ bias,
                                              const float* __restrict__ residual,
                                              float* __restrict__ Cout) {
  constexpr int BK = 128;
  const int K = CH, N = CH;
  __shared__ __align__(16) u8 lA[128 * BK];
  __shared__ __align__(16) u8 lB[128 * BK];
  const int bm = blockIdx.y * 128, bn = blockIdx.x * 128;
  const int tid = threadIdx.x, lane = tid & 63, wid = tid >> 6;
  const int wm = (wid >> 1) * 64, wn = (wid & 1) * 64;
  const int r0 = lane & 15, h = lane >> 4;

  const int srow = lane >> 3;
  const int scol = ((lane & 7) * 16) ^ ((srow & 7) << 4);
  size_t aoff[4], boff[4];
#pragma unroll
  for (int s = 0; s < 4; ++s) {
    int row = wid * 32 + s * 8 + srow;
    aoff[s] = (size_t)(bm + row) * K + scol;
    boff[s] = (size_t)(bn + row) * K + scol;
  }

  f32x4 acc[4][4] = {};
  for (int kt = 0; kt < K; kt += BK) {
    __syncthreads();
#pragma unroll
    for (int s = 0; s < 4; ++s) {
      GLOAD16(A + aoff[s] + kt, &lA[(wid * 4 + s) * 1024]);
      GLOAD16(Bt + boff[s] + kt, &lB[(wid * 4 + s) * 1024]);
    }
    __syncthreads();
    i32x8 bf[4];
#pragma unroll
    for (int j = 0; j < 4; ++j) RD8(bf[j], lB, wn + j * 16 + r0);
#pragma unroll
    for (int i = 0; i < 4; ++i) {
      i32x8 af;
      RD8(af, lA, wm + i * 16 + r0);
#pragma unroll
      for (int j = 0; j < 4; ++j)
        acc[i][j] = __builtin_amdgcn_mfma_scale_f32_16x16x128_f8f6f4(
            af, bf[j], acc[i][j], 0, 0, 0, 127, 0, 127);
    }
  }

#pragma unroll
  for (int j = 0; j < 4; ++j) {
    int n = bn + wn + j * 16 + r0;
    float bvv = bias[n];
#pragma unroll
    for (int i = 0; i < 4; ++i) {
      int m0 = bm + wm + i * 16 + h * 4;
#pragma unroll
      for (int r = 0; r < 4; ++r) {
        size_t idx = (size_t)(m0 + r) * N + n;
        Cout[idx] = acc[i][j][r] + bvv + residual[idx];
      }
    }
  }
}

extern "C" void kernel_launch(void* const* d_in, const int* in_sizes, int n_in,
                              void* d_out, int out_size, void* d_ws, size_t ws_size,
                              hipStream_t stream) {
  (void)in_sizes; (void)n_in; (void)out_size;
  const float* x     = (const float*)d_in[0];
  const float* gamma = (const float*)d_in[1];
  const float* beta  = (const float*)d_in[2];
  const float* Wq    = (const float*)d_in[3];
  const float* bq    = (const float*)d_in[4];
  const float* Wk    = (const float*)d_in[5];
  const float* bk    = (const float*)d_in[6];
  const float* Wv    = (const float*)d_in[7];
  const float* bv    = (const float*)d_in[8];
  const float* Wp    = (const float*)d_in[9];
  const float* bp    = (const float*)d_in[10];
  float* out = (float*)d_out;

  char* ws = (char*)d_ws;
  size_t off = 0;
  auto alloc = [&](size_t bytes) -> void* {
    void* p = ws + off;
    off += (bytes + 255) & ~(size_t)255;
    return p;
  };
  const size_t X8  = (size_t)TOKENS * CH;         // 8 MB fp8
  const size_t X4  = (size_t)TOKENS * CH / 2;     // 4 MB fp4
  const size_t W8  = (size_t)CH * CH;             // 0.25 MB fp8
  const size_t S8B = (size_t)HW * HW;             // 16.8 MB fp8 per batch
  const size_t LS  = (size_t)4 * 64 * HW * sizeof(float);  // 4 MB partial rowsums
  const size_t need_all = 1024 * 1024 + LS + 2 * X8 + 3 * X4 + 4 * W8 + 4 * S8B;
  const bool big = ws_size >= need_all;           // deterministic across calls

  float2* stats    = (float2*)alloc(128 * sizeof(float2));
  float* lsum_part = (float*)alloc(LS);           // [z][64][HW]
  u8* xn8   = (u8*)alloc(X8);    // fp8 normalized input
  u8* O8    = (u8*)alloc(X8);    // fp8 attention out
  u8* Q4    = (u8*)alloc(X4);    // fp4 (x4 pre-scaled), kappa-c channel order
  u8* K4    = (u8*)alloc(X4);
  u8* V4    = (u8*)alloc(X4);    // fp4 [B][CH][HW/2]
  u8* Wqkv8 = (u8*)alloc(3 * W8);
  u8* Wp8   = (u8*)alloc(W8);
  u8* S8    = (u8*)alloc(big ? 4 * S8B : S8B);

  gn_stats<<<128, 256, 0, stream>>>(x, stats);
  gn_apply8<<<TOKENS * CH / 8 / 256, 256, 0, stream>>>(x, gamma, beta, stats, xn8);
  transpose_w8<<<dim3(16, 16, 4), dim3(32, 8), 0, stream>>>(
      Wq, Wk, Wv, Wp, Wqkv8, Wqkv8 + (size_t)CH * CH, Wqkv8 + 2 * (size_t)CH * CH, Wp8);

  qkvmx<<<dim3(1536 / 128, TOKENS / 128), 256, 0, stream>>>(
      xn8, Wqkv8, bq, bk, bv, Q4, K4, V4);

  const float scl = 0.044194173824159216f;  // 1/sqrt(512)
  const size_t sQ = (size_t)HW * 256;       // fp4 row = 256 B
  if (big) {
    sgemm4<<<dim3(32, 32, 4), 256, 0, stream>>>(
        K4, Q4, lsum_part, S8, scl, sQ, sQ, (size_t)HW * HW);
    pv84<<<dim3(512, 1, 1), 256, 0, stream>>>(S8, V4, lsum_part, O8);
  } else {
    for (int b = 0; b < 4; ++b) {
      sgemm4<<<dim3(32, 32, 1), 256, 0, stream>>>(
          K4 + (size_t)b * sQ, Q4 + (size_t)b * sQ,
          lsum_part + (size_t)b * 64 * HW, S8, scl, 0, 0, 0);
      pv84<<<dim3(4, 32, 1), 256, 0, stream>>>(
          S8, V4 + (size_t)b * CH * (HW / 2),
          lsum_part + (size_t)b * 64 * HW, O8 + (size_t)b * HW * CH);
    }
  }

  projmx<<<dim3(4, TOKENS / 128), 256, 0, stream>>>(O8, Wp8, bp, x, out);
}